// Round 2
// baseline (64.676 us; speedup 1.0000x reference)
//
#include <hip/hip_runtime.h>
#include <math.h>

#define NMAT (192*192*192)   // 7,077,888 matrices
#define MPB  1024            // matrices per block (4 per thread, 256 threads)

__global__ __launch_bounds__(256, 4) void eig3_kernel(const float4* __restrict__ H4,
                                                      float4* __restrict__ out4) {
    __shared__ float lds[MPB * 9];          // 36 KB
    float4* lds4 = (float4*)lds;
    const int t = threadIdx.x;
    const long long blk = blockIdx.x;

    // Stage 1024 matrices = 9216 floats = 2304 float4, perfectly coalesced.
    const long long ibase = blk * 2304LL;
#pragma unroll
    for (int k = 0; k < 9; ++k)
        lds4[t + 256 * k] = H4[ibase + t + 256 * k];
    __syncthreads();

    float res[4][3];
#pragma unroll
    for (int s = 0; s < 4; ++s) {
        const int m = t + 256 * s;          // strided ownership: (9t+j)%32 banks -> conflict-free
        float h[9];
#pragma unroll
        for (int j = 0; j < 9; ++j)
            h[j] = lds[m * 9 + j];

        const float q = (h[0] + h[4] + h[8]) * (1.0f / 3.0f);
        const float c00 = h[0] - q, c01 = h[1],     c02 = h[2];
        const float c10 = h[3],     c11 = h[4] - q, c12 = h[5];
        const float c20 = h[6],     c21 = h[7],     c22 = h[8] - q;
        const float ss = c00*c00 + c01*c01 + c02*c02
                       + c10*c10 + c11*c11 + c12*c12
                       + c20*c20 + c21*c21 + c22*c22;
        const float p = sqrtf(ss * (1.0f / 6.0f));
        const float inv = 1.0f / (p + 1e-10f);
        const float b00 = c00*inv, b01 = c01*inv, b02 = c02*inv;
        const float b10 = c10*inv, b11 = c11*inv, b12 = c12*inv;
        const float b20 = c20*inv, b21 = c21*inv, b22 = c22*inv;
        const float detB = b00*(b11*b22 - b12*b21)
                         - b01*(b10*b22 - b12*b20)
                         + b02*(b10*b21 - b11*b20);
        const float x = fminf(fmaxf(detB * 0.5f, -1.0f), 1.0f);
        const float theta = acosf(x) * (1.0f / 3.0f);

        float st, ct;
        __sincosf(theta, &st, &ct);
        const float r3 = 1.73205080756887729f;   // sqrt(3)
        // e0 = 2p*cos(th)+q ; e{1,2} = p*(-cos(th) ∓ sqrt(3)*sin(th)) + q
        const float e0 = 2.0f * p * ct + q;
        const float e1 = p * (-ct - r3 * st) + q;
        const float e2 = p * (-ct + r3 * st) + q;

        const float a  = fminf(e0, e1), b = fmaxf(e0, e1);
        const float hi = fmaxf(b, e2),  c = fminf(b, e2);
        const float lo = fminf(a, c),   mid = fmaxf(a, c);
        res[s][0] = lo; res[s][1] = mid; res[s][2] = hi;
    }
    __syncthreads();   // lds reused for output staging

#pragma unroll
    for (int s = 0; s < 4; ++s) {
        const int m = t + 256 * s;          // (3t+c)%32 banks -> conflict-free
        lds[m * 3 + 0] = res[s][0];
        lds[m * 3 + 1] = res[s][1];
        lds[m * 3 + 2] = res[s][2];
    }
    __syncthreads();

    // 1024 matrices * 3 = 3072 floats = 768 float4, coalesced.
    const long long obase = blk * 768LL;
#pragma unroll
    for (int k = 0; k < 3; ++k)
        out4[obase + t + 256 * k] = lds4[t + 256 * k];
}

extern "C" void kernel_launch(void* const* d_in, const int* in_sizes, int n_in,
                              void* d_out, int out_size, void* d_ws, size_t ws_size,
                              hipStream_t stream) {
    const float4* H4 = (const float4*)d_in[0];
    float4* out4 = (float4*)d_out;
    const int nblocks = NMAT / MPB;   // 6912, no tail
    eig3_kernel<<<nblocks, 256, 0, stream>>>(H4, out4);
}